// Round 9
// baseline (496.513 us; speedup 1.0000x reference)
//
#include <hip/hip_runtime.h>

#define BATCH 65536

typedef float f32x4 __attribute__((ext_vector_type(4)));
typedef _Float16 f16x8 __attribute__((ext_vector_type(8)));

__device__ __forceinline__ void async_ld16(const void* g, void* l) {
  __builtin_amdgcn_global_load_lds(
      (const __attribute__((address_space(1))) void*)g,
      (__attribute__((address_space(3))) void*)l, 16, 0, 0);
}

__device__ __forceinline__ float act_f(float x, float a0, float a1, float a2,
                                       float a3, float a4) {
  float ax = fabsf(x);
  float e = __builtin_amdgcn_exp2f(ax * -2.8853900817779268f);
  float th = (1.0f - e) * __builtin_amdgcn_rcpf(1.0f + e);
  th = copysignf(th, x);
  float arg = fmaf(a1, x, a2);
  float rev = arg * 0.15915494309189535f;
  rev -= floorf(rev);
  float s = __builtin_amdgcn_sinf(rev);
  return fmaf(a3, x, fmaf(a0 * th, s, a4));
}

// split + transpose weights: W[K][N] fp32 -> Wt_hi/lo[N][K] fp16.
// i indexes the OUTPUT (n,k): writes coalesced, reads strided.
__global__ __launch_bounds__(256) void splitT_k(const float* __restrict__ W,
                                                _Float16* __restrict__ hi,
                                                _Float16* __restrict__ lo,
                                                int K, int N) {
  const int i = blockIdx.x * 256 + threadIdx.x;
  if (i >= K * N) return;
  const int n = i / K, k = i % K;
  const float w = W[(size_t)k * N + n];
  const _Float16 h = (_Float16)w;
  hi[i] = h;
  lo[i] = (_Float16)(w - (float)h);
}

__device__ __forceinline__ f32x4 mfma3(f16x8 ah, f16x8 al, f16x8 bh, f16x8 bl,
                                       f32x4 c) {
  c = __builtin_amdgcn_mfma_f32_16x16x32_f16(ah, bh, c, 0, 0, 0);
  c = __builtin_amdgcn_mfma_f32_16x16x32_f16(ah, bl, c, 0, 0, 0);
  c = __builtin_amdgcn_mfma_f32_16x16x32_f16(al, bh, c, 0, 0, 0);
  return c;
}

// C = A @ B, m97 geometry: block 128x128, BK=32, 4 waves as 2x2, wave tile
// 64x64 (acc[4][4]). A: fp32 (AF32) or fp16 hi/lo planes; B: Wt[N][K] hi/lo.
// 3-product compensation, identical per-element k/product order as before.
// LDS staged via global_load_lds with PRE-SWIZZLED global source + swizzled
// ds_read (XOR involution): fp16 planes slot^=(row&3) (8-way -> 4-way
// conflict), fp32 tile slot^=(row&7) (16-way -> 2-way).
// Epilogue: bias + activation -> hi/lo fp16 planes (stride N).
template <bool AF32>
__global__ __launch_bounds__(256, 4) void gemm128(
    const float* __restrict__ Af, const _Float16* __restrict__ Ahi,
    const _Float16* __restrict__ Alo, const _Float16* __restrict__ Bhi,
    const _Float16* __restrict__ Blo, const float* __restrict__ bias,
    const float* __restrict__ ap, _Float16* __restrict__ Chi,
    _Float16* __restrict__ Clo, int K, int N) {
  // sA: AF32 ? fp32[128][32] (16 KB) : 2 fp16 planes [128][32] (8 KB each)
  // sB: 2 fp16 planes [128][32] (8 KB each)
  __shared__ __align__(16) _Float16 sA[8192];
  __shared__ __align__(16) _Float16 sB[8192];

  const int tid = threadIdx.x;
  const int wv = tid >> 6;
  const int lane = tid & 63;
  const int wm = wv >> 1, wn = wv & 1;
  const int m16 = lane & 15, quad = lane >> 4;
  const int qsw = quad ^ (m16 & 3);  // fp16-plane swizzled 16B slot
  const int col0 = blockIdx.x * 128;
  const int row0 = blockIdx.y * 128;

  f32x4 acc[4][4];
  const f32x4 zero = {0.f, 0.f, 0.f, 0.f};
#pragma unroll
  for (int i = 0; i < 4; ++i)
#pragma unroll
    for (int j = 0; j < 4; ++j) acc[i][j] = zero;

  const int nk = K >> 5;
  for (int kt = 0; kt < nk; ++kt) {
    const int k0 = kt << 5;
    // ---- stage A ----
    if (AF32) {
      // 16 chunks of 1KB (8 rows x 128B); wave stages 4. swizzle slot^(r&7)
      float* sAf = (float*)sA;
#pragma unroll
      for (int t = 0; t < 4; ++t) {
        const int c = wv * 4 + t;
        const int r = c * 8 + (lane >> 3);
        const int sl = (lane & 7) ^ (r & 7);
        const size_t ga = (size_t)(row0 + r) * K + k0 + sl * 4;
        async_ld16(Af + ga, (void*)&sAf[c * 256]);
      }
    } else {
      // per plane 8 chunks (16 rows x 64B); wave stages 2. slot^(r&3)
#pragma unroll
      for (int t = 0; t < 2; ++t) {
        const int c = wv * 2 + t;
        const int r = c * 16 + (lane >> 2);
        const int sl = (lane & 3) ^ (r & 3);
        const size_t ga = (size_t)(row0 + r) * K + k0 + sl * 8;
        async_ld16(Ahi + ga, (void*)&sA[c * 512]);
        async_ld16(Alo + ga, (void*)&sA[4096 + c * 512]);
      }
    }
    // ---- stage B: per plane 8 chunks; wave stages 2. slot^(col&3) ----
#pragma unroll
    for (int t = 0; t < 2; ++t) {
      const int c = wv * 2 + t;
      const int col = c * 16 + (lane >> 2);
      const int sl = (lane & 3) ^ (col & 3);
      const size_t gb = (size_t)(col0 + col) * K + k0 + sl * 8;
      async_ld16(Bhi + gb, (void*)&sB[c * 512]);
      async_ld16(Blo + gb, (void*)&sB[4096 + c * 512]);
    }
    __syncthreads();

    // ---- A fragments (swizzled reads) ----
    f16x8 ah[4], al[4];
#pragma unroll
    for (int tm = 0; tm < 4; ++tm) {
      const int arow = wm * 64 + tm * 16 + m16;  // arow&7 == m16&7
      if (AF32) {
        const float* pa = (const float*)sA + arow * 32;
        const int s0 = (2 * quad) ^ (m16 & 7);
        const int s1 = (2 * quad + 1) ^ (m16 & 7);
        const f32x4 x0 = *(const f32x4*)(pa + s0 * 4);
        const f32x4 x1 = *(const f32x4*)(pa + s1 * 4);
#pragma unroll
        for (int j = 0; j < 4; ++j) {
          const _Float16 h0 = (_Float16)x0[j];
          ah[tm][j] = h0;
          al[tm][j] = (_Float16)(x0[j] - (float)h0);
          const _Float16 h1 = (_Float16)x1[j];
          ah[tm][4 + j] = h1;
          al[tm][4 + j] = (_Float16)(x1[j] - (float)h1);
        }
      } else {
        ah[tm] = *(const f16x8*)&sA[arow * 32 + qsw * 8];
        al[tm] = *(const f16x8*)&sA[4096 + arow * 32 + qsw * 8];
      }
    }
    // ---- B fragments + MFMA, n-tiles streamed ----
#pragma unroll
    for (int tn = 0; tn < 4; ++tn) {
      const int bcol = wn * 64 + tn * 16 + m16;
      const f16x8 bh = *(const f16x8*)&sB[bcol * 32 + qsw * 8];
      const f16x8 bl = *(const f16x8*)&sB[4096 + bcol * 32 + qsw * 8];
#pragma unroll
      for (int tm = 0; tm < 4; ++tm)
        acc[tm][tn] = mfma3(ah[tm], al[tm], bh, bl, acc[tm][tn]);
    }
    __syncthreads();
  }

  // ---- epilogue: C/D layout col=lane&15, row=quad*4+reg ----
#pragma unroll
  for (int tn = 0; tn < 4; ++tn) {
    const int col = col0 + wn * 64 + tn * 16 + m16;
    const float bs = bias[col];
    const float p0 = ap[col * 5 + 0];
    const float p1 = ap[col * 5 + 1];
    const float p2 = ap[col * 5 + 2];
    const float p3 = ap[col * 5 + 3];
    const float p4 = ap[col * 5 + 4];
#pragma unroll
    for (int tm = 0; tm < 4; ++tm) {
      const int row = row0 + wm * 64 + tm * 16 + quad * 4;
#pragma unroll
      for (int r = 0; r < 4; ++r) {
        const float y = act_f(acc[tm][tn][r] + bs, p0, p1, p2, p3, p4);
        const size_t o = (size_t)(row + r) * N + col;
        const _Float16 h = (_Float16)y;
        Chi[o] = h;
        Clo[o] = (_Float16)(y - (float)h);
      }
    }
  }
}

// GEMM3 + fused softmax (byte-identical to the verified r8 FINAL path).
// Block 64 rows x 256 cols (full N), 4 waves 2x2, K=512.
__global__ __launch_bounds__(256, 4) void gemm_final(
    const _Float16* __restrict__ Ahi, const _Float16* __restrict__ Alo,
    const _Float16* __restrict__ Bhi, const _Float16* __restrict__ Blo,
    const float* __restrict__ bias, const float* __restrict__ ap,
    float* __restrict__ Cout, int K) {
  __shared__ __align__(16) _Float16 sA[4096];
  __shared__ __align__(16) _Float16 sB[16384];

  const int tid = threadIdx.x;
  const int wv = tid >> 6;
  const int lane = tid & 63;
  const int wm = wv >> 1, wn = wv & 1;
  const int m16 = lane & 15, quad = lane >> 4;
  const int row0 = blockIdx.x * 64;

  f32x4 acc[2][8];
  const f32x4 zero = {0.f, 0.f, 0.f, 0.f};
#pragma unroll
  for (int i = 0; i < 2; ++i)
#pragma unroll
    for (int j = 0; j < 8; ++j) acc[i][j] = zero;

  const int nk = K >> 5;
  for (int kt = 0; kt < nk; ++kt) {
    const int k0 = kt << 5;
    // per plane: 4 chunks (16 rows x 64B); wave stages chunk wv of each
    {
      const int r = wv * 16 + (lane >> 2);
      const size_t ga = (size_t)(row0 + r) * K + k0 + (lane & 3) * 8;
      async_ld16(Ahi + ga, (void*)&sA[wv * 512]);
      async_ld16(Alo + ga, (void*)&sA[2048 + wv * 512]);
    }
    // B: per plane 16 chunks (16 cols x 64B); wave stages 4
#pragma unroll
    for (int t = 0; t < 4; ++t) {
      const int c = wv * 4 + t;
      const int col = c * 16 + (lane >> 2);
      const size_t gb = (size_t)col * K + k0 + (lane & 3) * 8;
      async_ld16(Bhi + gb, (void*)&sB[c * 512]);
      async_ld16(Blo + gb, (void*)&sB[8192 + c * 512]);
    }
    __syncthreads();

    f16x8 ah[2], al[2];
#pragma unroll
    for (int tm = 0; tm < 2; ++tm) {
      const int arow = wm * 32 + tm * 16 + m16;
      ah[tm] = *(const f16x8*)&sA[arow * 32 + quad * 8];
      al[tm] = *(const f16x8*)&sA[2048 + arow * 32 + quad * 8];
    }
#pragma unroll
    for (int tn = 0; tn < 8; ++tn) {
      const int bcol = wn * 128 + tn * 16 + m16;
      const f16x8 bh = *(const f16x8*)&sB[bcol * 32 + quad * 8];
      const f16x8 bl = *(const f16x8*)&sB[8192 + bcol * 32 + quad * 8];
#pragma unroll
      for (int tm = 0; tm < 2; ++tm)
        acc[tm][tn] = mfma3(ah[tm], al[tm], bh, bl, acc[tm][tn]);
    }
    __syncthreads();
  }

  // bias + activation in place, then in-block softmax over 256 cols.
  float* const redf = (float*)sA;        // [2 wn][64 rows]
  float* const rowm = (float*)sA + 128;  // [64] row max
  float* const rowi = (float*)sA + 192;  // [64] row 1/sum
#pragma unroll
  for (int tn = 0; tn < 8; ++tn) {
    const int col = wn * 128 + tn * 16 + m16;
    const float bs = bias[col];
    const float p0 = ap[col * 5 + 0];
    const float p1 = ap[col * 5 + 1];
    const float p2 = ap[col * 5 + 2];
    const float p3 = ap[col * 5 + 3];
    const float p4 = ap[col * 5 + 4];
#pragma unroll
    for (int tm = 0; tm < 2; ++tm)
#pragma unroll
      for (int r = 0; r < 4; ++r)
        acc[tm][tn][r] = act_f(acc[tm][tn][r] + bs, p0, p1, p2, p3, p4);
  }
#pragma unroll
  for (int tm = 0; tm < 2; ++tm)
#pragma unroll
    for (int r = 0; r < 4; ++r) {
      float m = acc[tm][0][r];
#pragma unroll
      for (int tn = 1; tn < 8; ++tn) m = fmaxf(m, acc[tm][tn][r]);
#pragma unroll
      for (int off = 1; off < 16; off <<= 1) m = fmaxf(m, __shfl_xor(m, off));
      if (m16 == 0) {
        const int rowl = wm * 32 + tm * 16 + quad * 4 + r;
        redf[wn * 64 + rowl] = m;
      }
    }
  __syncthreads();
  if (tid < 64) rowm[tid] = fmaxf(redf[tid], redf[64 + tid]);
  __syncthreads();
#pragma unroll
  for (int tm = 0; tm < 2; ++tm)
#pragma unroll
    for (int r = 0; r < 4; ++r) {
      const int rowl = wm * 32 + tm * 16 + quad * 4 + r;
      const float m = rowm[rowl];
      float s = 0.f;
#pragma unroll
      for (int tn = 0; tn < 8; ++tn) {
        const float e =
            __builtin_amdgcn_exp2f((acc[tm][tn][r] - m) * 1.4426950408889634f);
        acc[tm][tn][r] = e;
        s += e;
      }
#pragma unroll
      for (int off = 1; off < 16; off <<= 1) s += __shfl_xor(s, off);
      if (m16 == 0) redf[wn * 64 + rowl] = s;
    }
  __syncthreads();
  if (tid < 64) rowi[tid] = __builtin_amdgcn_rcpf(redf[tid] + redf[64 + tid]);
  __syncthreads();
#pragma unroll
  for (int tm = 0; tm < 2; ++tm)
#pragma unroll
    for (int r = 0; r < 4; ++r) {
      const int rowl = wm * 32 + tm * 16 + quad * 4 + r;
      const float inv = rowi[rowl];
#pragma unroll
      for (int tn = 0; tn < 8; ++tn) {
        const int col = wn * 128 + tn * 16 + m16;
        Cout[(size_t)(row0 + rowl) * 256 + col] = acc[tm][tn][r] * inv;
      }
    }
}

extern "C" void kernel_launch(void* const* d_in, const int* in_sizes, int n_in,
                              void* d_out, int out_size, void* d_ws,
                              size_t ws_size, hipStream_t stream) {
  const float* data = (const float*)d_in[0];
  const float* W1 = (const float*)d_in[1];
  const float* b1 = (const float*)d_in[2];
  const float* a1 = (const float*)d_in[3];
  const float* W2 = (const float*)d_in[4];
  const float* b2 = (const float*)d_in[5];
  const float* a2 = (const float*)d_in[6];
  const float* W3 = (const float*)d_in[7];
  const float* b3 = (const float*)d_in[8];
  const float* a3 = (const float*)d_in[9];
  float* out = (float*)d_out;

  char* ws = (char*)d_ws;
  const size_t KB = 1024, MB = 1024 * 1024;
  _Float16* w1hi = (_Float16*)(ws + 0 * KB);  // Wt1[512][256]
  _Float16* w1lo = (_Float16*)(ws + 256 * KB);
  _Float16* w2hi = (_Float16*)(ws + 512 * KB);  // Wt2[512][512]
  _Float16* w2lo = (_Float16*)(ws + 1024 * KB);
  _Float16* w3hi = (_Float16*)(ws + 1536 * KB);  // Wt3[256][512]
  _Float16* w3lo = (_Float16*)(ws + 1792 * KB);
  // h1 hi/lo: 65536x512 fp16 = 64 MB each; h2lo 64 MB; h2hi lives in d_out
  // (row-disjoint final blocks; epilogue writes after all K-loop reads)
  _Float16* h1hi = (_Float16*)(ws + 2 * MB);
  _Float16* h1lo = (_Float16*)(ws + 2 * MB + (size_t)BATCH * 512 * 2);
  _Float16* h2lo = (_Float16*)(ws + 2 * MB + (size_t)BATCH * 512 * 4);
  _Float16* h2hi = (_Float16*)d_out;

  splitT_k<<<(256 * 512 + 255) / 256, 256, 0, stream>>>(W1, w1hi, w1lo, 256, 512);
  splitT_k<<<(512 * 512 + 255) / 256, 256, 0, stream>>>(W2, w2hi, w2lo, 512, 512);
  splitT_k<<<(512 * 256 + 255) / 256, 256, 0, stream>>>(W3, w3hi, w3lo, 512, 256);

  // grid: x = N-tiles (fastest -> strip-mates dispatch-adjacent, L3-hot A),
  //       y = 128-row M-strips
  gemm128<true><<<dim3(4, BATCH / 128), 256, 0, stream>>>(
      data, nullptr, nullptr, w1hi, w1lo, b1, a1, h1hi, h1lo, 256, 512);
  gemm128<false><<<dim3(4, BATCH / 128), 256, 0, stream>>>(
      nullptr, h1hi, h1lo, w2hi, w2lo, b2, a2, h2hi, h2lo, 512, 512);
  gemm_final<<<BATCH / 64, 256, 0, stream>>>(h2hi, h2lo, w3hi, w3lo, b3, a3,
                                             out, 512);
}